// Round 2
// baseline (1527.948 us; speedup 1.0000x reference)
//
#include <hip/hip_runtime.h>
#include <math.h>

namespace {
constexpr int B_ = 128;
constexpr int N_ = 256;
constexpr int H_ = 128;
constexpr int M_TOTAL = B_ * N_;  // 32768 nodes
}

#define AS1 __attribute__((address_space(1)))
#define AS3 __attribute__((address_space(3)))

// async 16B global->LDS. LDS dest = wave-uniform base + lane*16 (HW-defined).
__device__ __forceinline__ void gl_lds16(const float* g, float* l) {
  __builtin_amdgcn_global_load_lds((const AS1 unsigned int*)g,
                                   (AS3 unsigned int*)l, 16, 0, 0);
}

// ---------------- weight pre-transpose ----------------
// in: W [2][O][I][8]  ->  out: Wt [I*8][2][O]   (pair-major, sin/cos, out)
template<int I, int O>
__global__ __launch_bounds__(256)
void wtr_kernel(const float* __restrict__ in, float* __restrict__ out) {
  int idx = blockIdx.x * 256 + threadIdx.x;
  constexpr int TOTAL = 2 * O * I * 8;
  if (idx >= TOTAL) return;
  int g = idx & 7;
  int t = idx >> 3;
  int i = t % I;
  int t2 = t / I;
  int o = t2 % O;
  int s = t2 / O;
  out[(size_t)((i * 8 + g) * 2 + s) * O + o] = in[idx];
}

// ---------------- Fourier-KAN linear ----------------
// out[node][o] = sum_{i,g} cos(x[n][i]*(g+1))*W0[o][i][g] + sin(..)*W1[o][i][g]
// Wt: [IN*8][2][128]. Block: 64 nodes x 128 outs, 256 thr, dbuf chunk=16 pairs.
template<int IN>
__global__ __launch_bounds__(256)
void fourier2(const float* __restrict__ x,   // [M][IN]
              const float* __restrict__ Wt,  // [IN*8][2][128]
              float* __restrict__ out)       // [M][128]
{
  constexpr int PAIRS = IN * 8;
  constexpr int CHUNKS = PAIRS / 16;   // 32 or 64 (2 inputs per chunk)
  __shared__ alignas(16) float wl[2][16][2][128];  // 32 KB
  __shared__ alignas(16) float fC[2][16][64];      // 8 KB
  __shared__ alignas(16) float fS[2][16][64];      // 8 KB

  const int tid = threadIdx.x;
  const int node0 = blockIdx.x * 64;
  const int og = tid & 15;     // outs og*4..+3 and og*4+64..+67
  const int ng = tid >> 4;     // nodes ng*4..+3
  const int lane = tid & 63;
  const int wave = tid >> 6;

  float acc[4][8];
  #pragma unroll
  for (int a = 0; a < 4; ++a)
    #pragma unroll
    for (int b = 0; b < 8; ++b) acc[a][b] = 0.f;

  // ---- prologue: stage chunk 0 into buf 0
  if (tid < 128) {
    const int il = tid >> 6, nd = tid & 63;
    float xv = x[(size_t)(node0 + nd) * IN + il];
    float s1, c1;
    sincosf(xv, &s1, &c1);
    float ckm = 1.f, skm = 0.f, ck = c1, sk = s1;
    #pragma unroll
    for (int g = 0; g < 8; ++g) {
      fC[0][il * 8 + g][nd] = ck;
      fS[0][il * 8 + g][nd] = sk;
      float cn = 2.f * c1 * ck - ckm, sn = 2.f * c1 * sk - skm;
      ckm = ck; skm = sk; ck = cn; sk = sn;
    }
  } else {
    const int wv = wave - 2;
    #pragma unroll
    for (int q = 0; q < 8; ++q) {
      int u = (wv * 8 + q) * 64 + lane;                    // float4 index
      gl_lds16(Wt + (size_t)u * 4,
               &wl[0][0][0][0] + (size_t)(wv * 8 + q) * 256);
    }
  }
  __syncthreads();

  int p = 0;
  for (int ic = 0; ic < CHUNKS; ++ic) {
    const int pn = p ^ 1;
    float xv = 0.f;
    const bool more = (ic + 1 < CHUNKS);
    if (more && tid >= 128) {
      const int wv = wave - 2;
      const float* wsrc = Wt + (size_t)(ic + 1) * 4096;    // 16*2*128 floats
      float* wdst = &wl[pn][0][0][0];
      #pragma unroll
      for (int q = 0; q < 8; ++q) {
        int u = (wv * 8 + q) * 64 + lane;
        gl_lds16(wsrc + (size_t)u * 4, wdst + (size_t)(wv * 8 + q) * 256);
      }
    }
    if (more && tid < 128) {
      xv = x[(size_t)(node0 + (tid & 63)) * IN + (ic + 1) * 2 + (tid >> 6)];
    }
    // ---- compute on buf p
    #pragma unroll
    for (int j = 0; j < 16; ++j) {
      float4 fc = *(const float4*)&fC[p][j][ng * 4];
      float4 fs = *(const float4*)&fS[p][j][ng * 4];
      float4 w0a = *(const float4*)&wl[p][j][0][og * 4];
      float4 w0b = *(const float4*)&wl[p][j][0][og * 4 + 64];
      float4 w1a = *(const float4*)&wl[p][j][1][og * 4];
      float4 w1b = *(const float4*)&wl[p][j][1][og * 4 + 64];
      float fcv[4] = {fc.x, fc.y, fc.z, fc.w};
      float fsv[4] = {fs.x, fs.y, fs.z, fs.w};
      float wa0[4] = {w0a.x, w0a.y, w0a.z, w0a.w};
      float wb0[4] = {w0b.x, w0b.y, w0b.z, w0b.w};
      float wa1[4] = {w1a.x, w1a.y, w1a.z, w1a.w};
      float wb1[4] = {w1b.x, w1b.y, w1b.z, w1b.w};
      #pragma unroll
      for (int nd = 0; nd < 4; ++nd) {
        #pragma unroll
        for (int oo = 0; oo < 4; ++oo) {
          acc[nd][oo]     += fcv[nd] * wa0[oo] + fsv[nd] * wa1[oo];
          acc[nd][4 + oo] += fcv[nd] * wb0[oo] + fsv[nd] * wb1[oo];
        }
      }
    }
    // ---- features for chunk ic+1 into buf pn
    if (more && tid < 128) {
      const int il = tid >> 6, nd = tid & 63;
      float s1, c1;
      sincosf(xv, &s1, &c1);
      float ckm = 1.f, skm = 0.f, ck = c1, sk = s1;
      #pragma unroll
      for (int g = 0; g < 8; ++g) {
        fC[pn][il * 8 + g][nd] = ck;
        fS[pn][il * 8 + g][nd] = sk;
        float cn = 2.f * c1 * ck - ckm, sn = 2.f * c1 * sk - skm;
        ckm = ck; skm = sk; ck = cn; sk = sn;
      }
    }
    __syncthreads();
    p ^= 1;
  }

  #pragma unroll
  for (int nd = 0; nd < 4; ++nd) {
    int row = node0 + ng * 4 + nd;
    float4 ra = {acc[nd][0], acc[nd][1], acc[nd][2], acc[nd][3]};
    float4 rb = {acc[nd][4], acc[nd][5], acc[nd][6], acc[nd][7]};
    *(float4*)&out[(size_t)row * H_ + og * 4] = ra;
    *(float4*)&out[(size_t)row * H_ + og * 4 + 64] = rb;
  }
}

// ---------------- Aggregation + residual + leaky ----------------
// h_out[b][m][o] = leaky( sum_k A[b][k>>2][k&3][m] * f[b][k>>2][o] + h_in[b][m][o] )
// Block: 64 m x 128 o, 256 thr, per-thread 4m x 8o, K chunk 32, dbuf.
__global__ __launch_bounds__(256)
void agg2(const float* __restrict__ A,     // [B][N][4][N]
          const float* __restrict__ f,     // [B][N][128]
          const float* __restrict__ h_in,  // [B][N][128]
          float* __restrict__ h_out)       // [B][N][128]
{
  __shared__ alignas(16) float As[2][32][64];    // 16 KB
  __shared__ alignas(16) float fsh[2][8][128];   // 8 KB
  const int tid = threadIdx.x;
  const int b = blockIdx.x >> 2;
  const int m0 = (blockIdx.x & 3) * 64;
  const int og = tid & 15;   // outs og*4, og*4+64
  const int mg = tid >> 4;   // m rows mg*4..+3
  const int wave = tid >> 6;

  float acc[4][8];
  #pragma unroll
  for (int i = 0; i < 4; ++i)
    #pragma unroll
    for (int j = 0; j < 8; ++j) acc[i][j] = 0.f;

  const float* Ab = A + (size_t)b * (N_ * 4 * N_) + m0;
  const float* fb = f + (size_t)b * (N_ * H_);

  // stage chunk 0
  #pragma unroll
  for (int q = 0; q < 2; ++q) {
    int v = q * 256 + tid;  // float4 index into [32][64]
    gl_lds16(Ab + (size_t)(v >> 4) * N_ + (v & 15) * 4,
             &As[0][0][0] + (size_t)(q * 256 + wave * 64) * 4);
  }
  gl_lds16(fb + (size_t)(tid >> 5) * H_ + (tid & 31) * 4,
           &fsh[0][0][0] + (size_t)(wave * 64) * 4);
  __syncthreads();

  int p = 0;
  for (int ch = 0; ch < 32; ++ch) {
    const int pn = p ^ 1;
    if (ch + 1 < 32) {
      const float* Asrc = Ab + (size_t)(ch + 1) * 32 * N_;
      #pragma unroll
      for (int q = 0; q < 2; ++q) {
        int v = q * 256 + tid;
        gl_lds16(Asrc + (size_t)(v >> 4) * N_ + (v & 15) * 4,
                 &As[pn][0][0] + (size_t)(q * 256 + wave * 64) * 4);
      }
      gl_lds16(fb + (size_t)((ch + 1) * 8 + (tid >> 5)) * H_ + (tid & 31) * 4,
               &fsh[pn][0][0] + (size_t)(wave * 64) * 4);
    }
    #pragma unroll
    for (int kk = 0; kk < 32; ++kk) {
      float4 a  = *(const float4*)&As[p][kk][mg * 4];
      float4 f0 = *(const float4*)&fsh[p][kk >> 2][og * 4];
      float4 f1 = *(const float4*)&fsh[p][kk >> 2][og * 4 + 64];
      float av[4] = {a.x, a.y, a.z, a.w};
      float fo[8] = {f0.x, f0.y, f0.z, f0.w, f1.x, f1.y, f1.z, f1.w};
      #pragma unroll
      for (int mi = 0; mi < 4; ++mi)
        #pragma unroll
        for (int oi = 0; oi < 8; ++oi)
          acc[mi][oi] += av[mi] * fo[oi];
    }
    __syncthreads();
    p ^= 1;
  }

  #pragma unroll
  for (int mi = 0; mi < 4; ++mi) {
    int row = b * N_ + m0 + mg * 4 + mi;
    const float* hr = &h_in[(size_t)row * H_];
    float* ho = &h_out[(size_t)row * H_];
    float4 r0 = *(const float4*)&hr[og * 4];
    float4 r1 = *(const float4*)&hr[og * 4 + 64];
    float4 o0, o1;
    float v;
    v = acc[mi][0] + r0.x; o0.x = v >= 0.f ? v : 0.01f * v;
    v = acc[mi][1] + r0.y; o0.y = v >= 0.f ? v : 0.01f * v;
    v = acc[mi][2] + r0.z; o0.z = v >= 0.f ? v : 0.01f * v;
    v = acc[mi][3] + r0.w; o0.w = v >= 0.f ? v : 0.01f * v;
    v = acc[mi][4] + r1.x; o1.x = v >= 0.f ? v : 0.01f * v;
    v = acc[mi][5] + r1.y; o1.y = v >= 0.f ? v : 0.01f * v;
    v = acc[mi][6] + r1.z; o1.z = v >= 0.f ? v : 0.01f * v;
    v = acc[mi][7] + r1.w; o1.w = v >= 0.f ? v : 0.01f * v;
    *(float4*)&ho[og * 4] = o0;
    *(float4*)&ho[og * 4 + 64] = o1;
  }
}

// ---------------- Masked mean pool + KAN head + sigmoid ----------------
__global__ __launch_bounds__(128)
void pool_kernel(const float* __restrict__ h,     // [B][N][128]
                 const int* __restrict__ mol,     // [B]
                 const float* __restrict__ Wout,  // [2][1][128][1]
                 const float* __restrict__ bout,  // [1][1]
                 float* __restrict__ out)         // [B]
{
  __shared__ float red[128];
  const int b = blockIdx.x;
  const int t = threadIdx.x;
  const int ms = mol[b];
  const float* hb = h + (size_t)b * N_ * H_;
  float sum = 0.f;
  for (int n = 0; n < ms; ++n) sum += hb[(size_t)n * H_ + t];
  float y = sum / (float)ms;
  float s1, c1;
  sincosf(y, &s1, &c1);
  red[t] = c1 * Wout[t] + s1 * Wout[H_ + t];
  __syncthreads();
  for (int sft = 64; sft > 0; sft >>= 1) {
    if (t < sft) red[t] += red[t + sft];
    __syncthreads();
  }
  if (t == 0) {
    float z = red[0] + bout[0];
    out[b] = 1.f / (1.f + expf(-z));
  }
}

extern "C" void kernel_launch(void* const* d_in, const int* in_sizes, int n_in,
                              void* d_out, int out_size, void* d_ws, size_t ws_size,
                              hipStream_t stream) {
  const float* V    = (const float*)d_in[0];
  const float* A    = (const float*)d_in[1];
  const int*   mol  = (const int*)d_in[2];
  const float* Win  = (const float*)d_in[3];
  const float* Wg   = (const float*)d_in[4];
  const float* Wout = (const float*)d_in[5];
  const float* bout = (const float*)d_in[6];
  float* out = (float*)d_out;

  float* h     = (float*)d_ws;                       // [32768][128]
  float* f     = h  + (size_t)M_TOTAL * H_;
  float* h2    = f  + (size_t)M_TOTAL * H_;
  float* wt_in = h2 + (size_t)M_TOTAL * H_;          // [512][2][128]
  float* wt_g0 = wt_in + 512 * 2 * H_;               // [1024][2][128]
  float* wt_g1 = wt_g0 + 1024 * 2 * H_;

  wtr_kernel<64, 128><<<(2 * 128 * 64 * 8) / 256, 256, 0, stream>>>(Win, wt_in);
  wtr_kernel<128, 128><<<(2 * 128 * 128 * 8) / 256, 256, 0, stream>>>(Wg, wt_g0);
  wtr_kernel<128, 128><<<(2 * 128 * 128 * 8) / 256, 256, 0, stream>>>(
      Wg + (size_t)2 * 128 * 128 * 8, wt_g1);

  fourier2<64><<<M_TOTAL / 64, 256, 0, stream>>>(V, wt_in, h);

  float* hc = h;
  float* hn = h2;
  const float* wt_g[2] = {wt_g0, wt_g1};
  for (int l = 0; l < 2; ++l) {
    fourier2<128><<<M_TOTAL / 64, 256, 0, stream>>>(hc, wt_g[l], f);
    agg2<<<B_ * 4, 256, 0, stream>>>(A, f, hc, hn);
    float* tmp = hc; hc = hn; hn = tmp;
  }

  pool_kernel<<<B_, 128, 0, stream>>>(hc, mol, Wout, bout, out);
}

// Round 3
// 967.398 us; speedup vs baseline: 1.5794x; 1.5794x over previous
//
#include <hip/hip_runtime.h>
#include <math.h>

namespace {
constexpr int B_ = 128;
constexpr int N_ = 256;
constexpr int H_ = 128;
constexpr int M_TOTAL = B_ * N_;  // 32768 nodes
}

#define AS1 __attribute__((address_space(1)))
#define AS3 __attribute__((address_space(3)))

// async 16B global->LDS. LDS dest = wave-uniform base + lane*16 (HW-defined).
__device__ __forceinline__ void gl_lds16(const float* g, float* l) {
  __builtin_amdgcn_global_load_lds((const AS1 unsigned int*)g,
                                   (AS3 unsigned int*)l, 16, 0, 0);
}

// ---------------- weight pre-transpose ----------------
// in: W [2][O][I][8]  ->  out: Wt [I*8][2][O]   (pair-major, sin/cos, out)
template<int I, int O>
__global__ __launch_bounds__(256)
void wtr_kernel(const float* __restrict__ in, float* __restrict__ out) {
  int idx = blockIdx.x * 256 + threadIdx.x;
  constexpr int TOTAL = 2 * O * I * 8;
  if (idx >= TOTAL) return;
  int g = idx & 7;
  int t = idx >> 3;
  int i = t % I;
  int t2 = t / I;
  int o = t2 % O;
  int s = t2 / O;
  out[(size_t)((i * 8 + g) * 2 + s) * O + o] = in[idx];
}

// ---------------- Fourier-KAN linear ----------------
// out[node][o] = sum_{i,g} cos(x[n][i]*(g+1))*W0[o][i][g] + sin(..)*W1[o][i][g]
// Wt: [IN*8][2][128]. Block: 64 nodes x 128 outs, 256 thr, dbuf chunk=16 pairs.
// VGPR budget: __launch_bounds__(256,4) caps at 128 regs (occupancy tier);
// #pragma unroll 2 on the inner loop keeps load pipelining shallow.
template<int IN>
__global__ __launch_bounds__(256, 4)
void fourier3(const float* __restrict__ x,   // [M][IN]
              const float* __restrict__ Wt,  // [IN*8][2][128]
              float* __restrict__ out)       // [M][128]
{
  constexpr int PAIRS = IN * 8;
  constexpr int CHUNKS = PAIRS / 16;   // 32 or 64 (2 inputs per chunk)
  __shared__ alignas(16) float wl[2][16][2][128];  // 32 KB
  __shared__ alignas(16) float fC[2][16][64];      // 8 KB
  __shared__ alignas(16) float fS[2][16][64];      // 8 KB

  const int tid = threadIdx.x;
  const int node0 = blockIdx.x * 64;
  const int og = tid & 15;     // outs og*4..+3 and og*4+64..+67
  const int ng = tid >> 4;     // nodes ng*4..+3
  const int lane = tid & 63;
  const int wave = tid >> 6;
  const int il = tid >> 6;     // (waves 0-1 only) input-within-chunk 0/1
  const int nd = tid & 63;     // (waves 0-1 only) node

  float acc[4][8];
  #pragma unroll
  for (int a = 0; a < 4; ++a)
    #pragma unroll
    for (int b = 0; b < 8; ++b) acc[a][b] = 0.f;

  // ---- prologue: chunk 0 features + weights into buf 0; preload x for chunk 1
  float xnext = 0.f;
  if (tid < 128) {
    float xv = x[(size_t)(node0 + nd) * IN + il];
    float s1, c1;
    sincosf(xv, &s1, &c1);
    float ckm = 1.f, skm = 0.f, ck = c1, sk = s1;
    #pragma unroll
    for (int g = 0; g < 8; ++g) {
      fC[0][il * 8 + g][nd] = ck;
      fS[0][il * 8 + g][nd] = sk;
      float cn = 2.f * c1 * ck - ckm, sn = 2.f * c1 * sk - skm;
      ckm = ck; skm = sk; ck = cn; sk = sn;
    }
    if (CHUNKS > 1) xnext = x[(size_t)(node0 + nd) * IN + 2 + il];
  } else {
    const int wv = wave - 2;
    #pragma unroll
    for (int q = 0; q < 8; ++q) {
      int u = (wv * 8 + q) * 64 + lane;                    // float4 index
      gl_lds16(Wt + (size_t)u * 4,
               &wl[0][0][0][0] + (size_t)(wv * 8 + q) * 256);
    }
  }
  __syncthreads();

  int p = 0;
  for (int ic = 0; ic < CHUNKS; ++ic) {
    const int pn = p ^ 1;
    const bool more = (ic + 1 < CHUNKS);
    if (more) {
      if (tid < 128) {
        // features for chunk ic+1 from pre-loaded xnext (no load stall)
        float s1, c1;
        sincosf(xnext, &s1, &c1);
        float ckm = 1.f, skm = 0.f, ck = c1, sk = s1;
        #pragma unroll
        for (int g = 0; g < 8; ++g) {
          fC[pn][il * 8 + g][nd] = ck;
          fS[pn][il * 8 + g][nd] = sk;
          float cn = 2.f * c1 * ck - ckm, sn = 2.f * c1 * sk - skm;
          ckm = ck; skm = sk; ck = cn; sk = sn;
        }
        if (ic + 2 < CHUNKS)
          xnext = x[(size_t)(node0 + nd) * IN + (ic + 2) * 2 + il];
      } else {
        const int wv = wave - 2;
        const float* wsrc = Wt + (size_t)(ic + 1) * 4096;  // 16*2*128 floats
        float* wdst = &wl[pn][0][0][0];
        #pragma unroll
        for (int q = 0; q < 8; ++q) {
          int u = (wv * 8 + q) * 64 + lane;
          gl_lds16(wsrc + (size_t)u * 4, wdst + (size_t)(wv * 8 + q) * 256);
        }
      }
    }
    // ---- compute on buf p (shallow unroll: keep VGPRs under the 128 tier)
    #pragma unroll 2
    for (int j = 0; j < 16; ++j) {
      float4 fc = *(const float4*)&fC[p][j][ng * 4];
      float4 fs = *(const float4*)&fS[p][j][ng * 4];
      float4 w0a = *(const float4*)&wl[p][j][0][og * 4];
      float4 w0b = *(const float4*)&wl[p][j][0][og * 4 + 64];
      float4 w1a = *(const float4*)&wl[p][j][1][og * 4];
      float4 w1b = *(const float4*)&wl[p][j][1][og * 4 + 64];
      float fcv[4] = {fc.x, fc.y, fc.z, fc.w};
      float fsv[4] = {fs.x, fs.y, fs.z, fs.w};
      float wa0[4] = {w0a.x, w0a.y, w0a.z, w0a.w};
      float wb0[4] = {w0b.x, w0b.y, w0b.z, w0b.w};
      float wa1[4] = {w1a.x, w1a.y, w1a.z, w1a.w};
      float wb1[4] = {w1b.x, w1b.y, w1b.z, w1b.w};
      #pragma unroll
      for (int nd2 = 0; nd2 < 4; ++nd2) {
        #pragma unroll
        for (int oo = 0; oo < 4; ++oo) {
          acc[nd2][oo]     += fcv[nd2] * wa0[oo] + fsv[nd2] * wa1[oo];
          acc[nd2][4 + oo] += fcv[nd2] * wb0[oo] + fsv[nd2] * wb1[oo];
        }
      }
    }
    __syncthreads();
    p ^= 1;
  }

  #pragma unroll
  for (int nd2 = 0; nd2 < 4; ++nd2) {
    int row = node0 + ng * 4 + nd2;
    float4 ra = {acc[nd2][0], acc[nd2][1], acc[nd2][2], acc[nd2][3]};
    float4 rb = {acc[nd2][4], acc[nd2][5], acc[nd2][6], acc[nd2][7]};
    *(float4*)&out[(size_t)row * H_ + og * 4] = ra;
    *(float4*)&out[(size_t)row * H_ + og * 4 + 64] = rb;
  }
}

// ---------------- Aggregation + residual + leaky ----------------
// h_out[b][m][o] = leaky( sum_k A[b][k>>2][k&3][m] * f[b][k>>2][o] + h_in[b][m][o] )
// Block: 64 m x 128 o, 256 thr, per-thread 4m x 8o, K chunk 32, dbuf.
__global__ __launch_bounds__(256)
void agg2(const float* __restrict__ A,     // [B][N][4][N]
          const float* __restrict__ f,     // [B][N][128]
          const float* __restrict__ h_in,  // [B][N][128]
          float* __restrict__ h_out)       // [B][N][128]
{
  __shared__ alignas(16) float As[2][32][64];    // 16 KB
  __shared__ alignas(16) float fsh[2][8][128];   // 8 KB
  const int tid = threadIdx.x;
  const int b = blockIdx.x >> 2;
  const int m0 = (blockIdx.x & 3) * 64;
  const int og = tid & 15;   // outs og*4, og*4+64
  const int mg = tid >> 4;   // m rows mg*4..+3
  const int wave = tid >> 6;

  float acc[4][8];
  #pragma unroll
  for (int i = 0; i < 4; ++i)
    #pragma unroll
    for (int j = 0; j < 8; ++j) acc[i][j] = 0.f;

  const float* Ab = A + (size_t)b * (N_ * 4 * N_) + m0;
  const float* fb = f + (size_t)b * (N_ * H_);

  // stage chunk 0
  #pragma unroll
  for (int q = 0; q < 2; ++q) {
    int v = q * 256 + tid;  // float4 index into [32][64]
    gl_lds16(Ab + (size_t)(v >> 4) * N_ + (v & 15) * 4,
             &As[0][0][0] + (size_t)(q * 256 + wave * 64) * 4);
  }
  gl_lds16(fb + (size_t)(tid >> 5) * H_ + (tid & 31) * 4,
           &fsh[0][0][0] + (size_t)(wave * 64) * 4);
  __syncthreads();

  int p = 0;
  for (int ch = 0; ch < 32; ++ch) {
    const int pn = p ^ 1;
    if (ch + 1 < 32) {
      const float* Asrc = Ab + (size_t)(ch + 1) * 32 * N_;
      #pragma unroll
      for (int q = 0; q < 2; ++q) {
        int v = q * 256 + tid;
        gl_lds16(Asrc + (size_t)(v >> 4) * N_ + (v & 15) * 4,
                 &As[pn][0][0] + (size_t)(q * 256 + wave * 64) * 4);
      }
      gl_lds16(fb + (size_t)((ch + 1) * 8 + (tid >> 5)) * H_ + (tid & 31) * 4,
               &fsh[pn][0][0] + (size_t)(wave * 64) * 4);
    }
    #pragma unroll
    for (int kk = 0; kk < 32; ++kk) {
      float4 a  = *(const float4*)&As[p][kk][mg * 4];
      float4 f0 = *(const float4*)&fsh[p][kk >> 2][og * 4];
      float4 f1 = *(const float4*)&fsh[p][kk >> 2][og * 4 + 64];
      float av[4] = {a.x, a.y, a.z, a.w};
      float fo[8] = {f0.x, f0.y, f0.z, f0.w, f1.x, f1.y, f1.z, f1.w};
      #pragma unroll
      for (int mi = 0; mi < 4; ++mi)
        #pragma unroll
        for (int oi = 0; oi < 8; ++oi)
          acc[mi][oi] += av[mi] * fo[oi];
    }
    __syncthreads();
    p ^= 1;
  }

  #pragma unroll
  for (int mi = 0; mi < 4; ++mi) {
    int row = b * N_ + m0 + mg * 4 + mi;
    const float* hr = &h_in[(size_t)row * H_];
    float* ho = &h_out[(size_t)row * H_];
    float4 r0 = *(const float4*)&hr[og * 4];
    float4 r1 = *(const float4*)&hr[og * 4 + 64];
    float4 o0, o1;
    float v;
    v = acc[mi][0] + r0.x; o0.x = v >= 0.f ? v : 0.01f * v;
    v = acc[mi][1] + r0.y; o0.y = v >= 0.f ? v : 0.01f * v;
    v = acc[mi][2] + r0.z; o0.z = v >= 0.f ? v : 0.01f * v;
    v = acc[mi][3] + r0.w; o0.w = v >= 0.f ? v : 0.01f * v;
    v = acc[mi][4] + r1.x; o1.x = v >= 0.f ? v : 0.01f * v;
    v = acc[mi][5] + r1.y; o1.y = v >= 0.f ? v : 0.01f * v;
    v = acc[mi][6] + r1.z; o1.z = v >= 0.f ? v : 0.01f * v;
    v = acc[mi][7] + r1.w; o1.w = v >= 0.f ? v : 0.01f * v;
    *(float4*)&ho[og * 4] = o0;
    *(float4*)&ho[og * 4 + 64] = o1;
  }
}

// ---------------- Masked mean pool + KAN head + sigmoid ----------------
__global__ __launch_bounds__(128)
void pool_kernel(const float* __restrict__ h,     // [B][N][128]
                 const int* __restrict__ mol,     // [B]
                 const float* __restrict__ Wout,  // [2][1][128][1]
                 const float* __restrict__ bout,  // [1][1]
                 float* __restrict__ out)         // [B]
{
  __shared__ float red[128];
  const int b = blockIdx.x;
  const int t = threadIdx.x;
  const int ms = mol[b];
  const float* hb = h + (size_t)b * N_ * H_;
  float sum = 0.f;
  for (int n = 0; n < ms; ++n) sum += hb[(size_t)n * H_ + t];
  float y = sum / (float)ms;
  float s1, c1;
  sincosf(y, &s1, &c1);
  red[t] = c1 * Wout[t] + s1 * Wout[H_ + t];
  __syncthreads();
  for (int sft = 64; sft > 0; sft >>= 1) {
    if (t < sft) red[t] += red[t + sft];
    __syncthreads();
  }
  if (t == 0) {
    float z = red[0] + bout[0];
    out[b] = 1.f / (1.f + expf(-z));
  }
}

extern "C" void kernel_launch(void* const* d_in, const int* in_sizes, int n_in,
                              void* d_out, int out_size, void* d_ws, size_t ws_size,
                              hipStream_t stream) {
  const float* V    = (const float*)d_in[0];
  const float* A    = (const float*)d_in[1];
  const int*   mol  = (const int*)d_in[2];
  const float* Win  = (const float*)d_in[3];
  const float* Wg   = (const float*)d_in[4];
  const float* Wout = (const float*)d_in[5];
  const float* bout = (const float*)d_in[6];
  float* out = (float*)d_out;

  float* h     = (float*)d_ws;                       // [32768][128]
  float* f     = h  + (size_t)M_TOTAL * H_;
  float* h2    = f  + (size_t)M_TOTAL * H_;
  float* wt_in = h2 + (size_t)M_TOTAL * H_;          // [512][2][128]
  float* wt_g0 = wt_in + 512 * 2 * H_;               // [1024][2][128]
  float* wt_g1 = wt_g0 + 1024 * 2 * H_;

  wtr_kernel<64, 128><<<(2 * 128 * 64 * 8) / 256, 256, 0, stream>>>(Win, wt_in);
  wtr_kernel<128, 128><<<(2 * 128 * 128 * 8) / 256, 256, 0, stream>>>(Wg, wt_g0);
  wtr_kernel<128, 128><<<(2 * 128 * 128 * 8) / 256, 256, 0, stream>>>(
      Wg + (size_t)2 * 128 * 128 * 8, wt_g1);

  fourier3<64><<<M_TOTAL / 64, 256, 0, stream>>>(V, wt_in, h);

  float* hc = h;
  float* hn = h2;
  const float* wt_g[2] = {wt_g0, wt_g1};
  for (int l = 0; l < 2; ++l) {
    fourier3<128><<<M_TOTAL / 64, 256, 0, stream>>>(hc, wt_g[l], f);
    agg2<<<B_ * 4, 256, 0, stream>>>(A, f, hc, hn);
    float* tmp = hc; hc = hn; hn = tmp;
  }

  pool_kernel<<<B_, 128, 0, stream>>>(hc, mol, Wout, bout, out);
}